// Round 17
// baseline (268.763 us; speedup 1.0000x reference)
//
#include <hip/hip_runtime.h>
#include <hip/hip_bf16.h>

// Problem constants
constexpr int N_   = 20000;
constexpr int E_   = 320000;
constexpr int M_   = 3;
constexpr int KIN  = 128;   // in_size
constexpr int H_   = 4;     // heads
constexpr int D_   = 64;    // per-head dim
constexpr int HD_  = 256;   // H*D
constexpr int HID_ = 128;   // semantic hidden
constexpr int MN_  = M_ * N_;   // 60000 segments
constexpr int ME_  = M_ * E_;   // 960000 edges
constexpr int NB_  = (MN_ + 255) / 256;  // 235 windows (256 rows each)
constexpr int EPB_ = 2048;               // edges per partition block
constexpr int NPB_ = (ME_ + EPB_ - 1) / EPB_;  // 469 partition blocks
constexpr int WS_SLOTS_ = 16;            // wsum slots per metapath (64 B apart)
constexpr int MAXQ_ = 1536;              // max edges per 64-row quarter (mean 1024, std 32)
#define NEG_SLOPE 0.2f

// Workspace layout (bytes)
constexpr size_t FEAT_OFF = 0;           // ushort[M*N*HD]  = 30,720,000 (FP16 feat)
constexpr size_t Z_OFF    = 30720000;    // ushort[M*N*HD]  (bf16 z)
constexpr size_t EBUF_OFF = 46080000;    // int   [M*E]     =  3,840,000 (window-grouped packed edges)
constexpr size_t EL_OFF   = 92160000;    // float [M*N*H]   =    960,000
constexpr size_t ER_OFF   = 93120000;    // float [M*N*H]   =    960,000
constexpr size_t WINC_OFF = 106080064;   // int   [256]     window edge counts   } memset
constexpr size_t WSUM_OFF = 106081088;   // float [3*16*16] = 3,072 hashed slots } together
constexpr size_t BO_OFF   = 106084160;   // int   [256]  window offsets (blockoff[NB_]=ME_)
constexpr size_t W1T_OFF  = 106085184;   // ushort[HID*HD] = 65,536 (bf16 W1 transposed)
constexpr size_t BCUR_OFF = 106150720;   // int   [256]    window write fronts (init by scan2w)
// wt overlaps the z region: z is written only by aggregate_win, which runs
// strictly after feat_gemm_mfma (sole consumer of wt).
constexpr size_t WT_OFF   = Z_OFF;       // ushort[M*HD*KIN] = 196,608

typedef __attribute__((ext_vector_type(8))) short short8;   // 8 bf16 (4 VGPRs)
typedef __attribute__((ext_vector_type(4))) float f32x4;    // MFMA accumulator

__device__ __forceinline__ float bf2f(ushort u) {
    union { unsigned int i; float f; } v; v.i = ((unsigned int)u) << 16; return v.f;
}
__device__ __forceinline__ ushort f2bf(float f) {
    union { float f; unsigned int i; } v; v.f = f;
    unsigned int i = v.i;
    unsigned int r = (i + 0x7fffu + ((i >> 16) & 1u)) >> 16;   // RNE
    return (ushort)r;
}
__device__ __forceinline__ ushort f2h(float f) {
    _Float16 h = (_Float16)f;
    ushort u; __builtin_memcpy(&u, &h, 2); return u;
}
__device__ __forceinline__ float h2f(ushort u) {
    _Float16 h; __builtin_memcpy(&h, &u, 2); return (float)h;   // fpext -> fma_mix fodder
}
// fast tanh: 1 - 2/(e^{2x}+1)
__device__ __forceinline__ float fast_tanh(float x) {
    float e = __expf(2.f * x);
    return 1.f - 2.f * __builtin_amdgcn_rcpf(e + 1.f);
}

// K0: fused prep (W->WT sigma-permuted bf16, W1->W1T bf16) + 235-bin window
// histogram (LDS + merged atomics). 1024 threads/block.
__global__ __launch_bounds__(1024) void prep_hist235(
    const float* __restrict__ W, const float* __restrict__ W1,
    const int* __restrict__ dst, ushort* __restrict__ wt,
    ushort* __restrict__ w1t, int* __restrict__ wincnt) {
    const int b = blockIdx.x, t = threadIdx.x;
    if (b < 32) {                                   // prep: 32*4096 = 131072 floats
        int f = b * 4096 + t * 4;
        if (f < 3 * HD_ * KIN) {                    // wt: 98304 elements
            int m = f >> 15, r = f & 32767, n = r >> 7, k0 = r & 127;
            int c = ((n & 15) << 4) | (n >> 4);     // sigma(n), self-inverse
            const float* src = W + (size_t)m * KIN * HD_ + c;
            ushort4 o;
            o.x = f2bf(src[(size_t)(k0 + 0) * HD_]);
            o.y = f2bf(src[(size_t)(k0 + 1) * HD_]);
            o.z = f2bf(src[(size_t)(k0 + 2) * HD_]);
            o.w = f2bf(src[(size_t)(k0 + 3) * HD_]);
            *(ushort4*)&wt[f] = o;
        } else {                                    // w1t: 32768 elements
            int f2 = f - 3 * HD_ * KIN;
            int n = f2 >> 8, k0 = f2 & 255;
            const float* src = W1 + n;
            ushort4 o;
            o.x = f2bf(src[(size_t)(k0 + 0) * HID_]);
            o.y = f2bf(src[(size_t)(k0 + 1) * HID_]);
            o.z = f2bf(src[(size_t)(k0 + 2) * HID_]);
            o.w = f2bf(src[(size_t)(k0 + 3) * HID_]);
            *(ushort4*)&w1t[f2] = o;
        }
    } else {                                        // histogram: 2048 edges/block
        __shared__ int hcnt[NB_];
        const int e0 = (b - 32) * EPB_;
        for (int i = t; i < NB_; i += 1024) hcnt[i] = 0;
        __syncthreads();
#pragma unroll
        for (int i = 0; i < 2; i++) {
            int e = e0 + i * 1024 + t;
            if (e < ME_) {
                int m = e / E_;
                int row = m * N_ + dst[e];
                atomicAdd(&hcnt[row >> 8], 1);
            }
        }
        __syncthreads();
        for (int i = t; i < NB_; i += 1024)
            if (hcnt[i]) atomicAdd(&wincnt[i], hcnt[i]);
    }
}

// K1: MFMA feat = h @ W[m] + fused el/er epilogue; feat stored FP16.
__global__ __launch_bounds__(128) void feat_gemm_mfma(
    const float* __restrict__ h, const ushort* __restrict__ wt,
    const float* __restrict__ al, const float* __restrict__ ar,
    ushort* __restrict__ feat, float* __restrict__ el, float* __restrict__ er) {
    const int tx   = threadIdx.x;
    const int wv   = tx >> 6;
    const int lane = tx & 63;
    const int l15  = lane & 15, kq = lane >> 4;
    const int m    = blockIdx.y;
    const int blockrow = blockIdx.x * 32;
    const int rowbase  = blockrow + wv * 16;

    __shared__ ushort hsm[32][KIN + 8];             // 8,704 B
#pragma unroll
    for (int i = 0; i < 8; i++) {
        int f4 = i * 128 + tx;                      // float4 idx 0..1023
        int r = f4 >> 5, k = (f4 & 31) * 4;
        float4 v = *(const float4*)&h[(size_t)(blockrow + r) * KIN + k];
        ushort4 o;
        o.x = f2bf(v.x); o.y = f2bf(v.y); o.z = f2bf(v.z); o.w = f2bf(v.w);
        *(ushort4*)&hsm[r][k] = o;
    }
    __syncthreads();

    f32x4 acc[16];
#pragma unroll
    for (int g = 0; g < 16; g++) acc[g] = {0.f, 0.f, 0.f, 0.f};

    const ushort* wb = wt + ((size_t)m * HD_ + l15) * KIN + kq * 8;
    const int arow = wv * 16 + l15;
    for (int kb = 0; kb < KIN; kb += 32) {
        short8 a = *(const short8*)&hsm[arow][kb + kq * 8];
#pragma unroll
        for (int g = 0; g < 16; g++) {
            short8 b = *(const short8*)&wb[(size_t)(16 * g) * KIN + kb];
            acc[g] = __builtin_amdgcn_mfma_f32_16x16x32_bf16(a, b, acc[g], 0, 0, 0);
        }
    }

    // feat store (fp16): acc[g][reg] = feat[row=rowbase+kq*4+reg][col=l15*16+g]
#pragma unroll
    for (int reg = 0; reg < 4; reg++) {
        int row = rowbase + kq * 4 + reg;
        short8 v0, v1;
#pragma unroll
        for (int g = 0; g < 8; g++) {
            v0[g] = (short)f2h(acc[g][reg]);
            v1[g] = (short)f2h(acc[g + 8][reg]);
        }
        size_t fo = ((size_t)m * N_ + row) * HD_ + l15 * 16;
        *(short8*)&feat[fo]     = v0;
        *(short8*)&feat[fo + 8] = v1;
    }

    const int head = l15 >> 2;
    const float* alp = al + ((size_t)(m * H_ + head)) * D_ + ((l15 & 3) << 4);
    const float* arp = ar + ((size_t)(m * H_ + head)) * D_ + ((l15 & 3) << 4);
    float4 av0 = *(const float4*)&alp[0],  av1 = *(const float4*)&alp[4];
    float4 av2 = *(const float4*)&alp[8],  av3 = *(const float4*)&alp[12];
    float4 rv0 = *(const float4*)&arp[0],  rv1 = *(const float4*)&arp[4];
    float4 rv2 = *(const float4*)&arp[8],  rv3 = *(const float4*)&arp[12];
    float pl[4], pr[4];
#pragma unroll
    for (int reg = 0; reg < 4; reg++) {
        pl[reg] = acc[0][reg]*av0.x + acc[1][reg]*av0.y + acc[2][reg]*av0.z + acc[3][reg]*av0.w
                + acc[4][reg]*av1.x + acc[5][reg]*av1.y + acc[6][reg]*av1.z + acc[7][reg]*av1.w
                + acc[8][reg]*av2.x + acc[9][reg]*av2.y + acc[10][reg]*av2.z + acc[11][reg]*av2.w
                + acc[12][reg]*av3.x + acc[13][reg]*av3.y + acc[14][reg]*av3.z + acc[15][reg]*av3.w;
        pr[reg] = acc[0][reg]*rv0.x + acc[1][reg]*rv0.y + acc[2][reg]*rv0.z + acc[3][reg]*rv0.w
                + acc[4][reg]*rv1.x + acc[5][reg]*rv1.y + acc[6][reg]*rv1.z + acc[7][reg]*rv1.w
                + acc[8][reg]*rv2.x + acc[9][reg]*rv2.y + acc[10][reg]*rv2.z + acc[11][reg]*rv2.w
                + acc[12][reg]*rv3.x + acc[13][reg]*rv3.y + acc[14][reg]*rv3.z + acc[15][reg]*rv3.w;
    }
#pragma unroll
    for (int off = 2; off; off >>= 1) {
#pragma unroll
        for (int reg = 0; reg < 4; reg++) {
            pl[reg] += __shfl_down(pl[reg], off, 4);
            pr[reg] += __shfl_down(pr[reg], off, 4);
        }
    }
    if ((l15 & 3) == 0) {
#pragma unroll
        for (int reg = 0; reg < 4; reg++) {
            int row = rowbase + kq * 4 + reg;
            int o = (m * N_ + row) * H_ + head;
            el[o] = pl[reg];
            er[o] = pr[reg];
        }
    }
}

// K2: scan 235 window counts -> blockoff + bcur; blockoff[NB_]=ME_.
__global__ __launch_bounds__(256) void scan2w(const int* __restrict__ wincnt,
                                              int* __restrict__ blockoff,
                                              int* __restrict__ bcur) {
    __shared__ int lds[256];
    const int t = threadIdx.x;
    int v = (t < NB_) ? wincnt[t] : 0;
    lds[t] = v;
    for (int s = 1; s < 256; s <<= 1) {
        __syncthreads();
        int tmp = (t >= s) ? lds[t - s] : 0;
        __syncthreads();
        lds[t] += tmp;
    }
    __syncthreads();
    if (t < NB_) {
        int off = lds[t] - v;
        blockoff[t] = off;
        bcur[t]     = off;
    }
    if (t == NB_) blockoff[NB_] = ME_;
}

// K3: radix partition — 1024 threads (unchanged).
__global__ __launch_bounds__(1024) void edge_partition(
    const int* __restrict__ src, const int* __restrict__ dst,
    int* __restrict__ bcur, int* __restrict__ ebuf) {
    const int t = threadIdx.x;
    const int e0 = blockIdx.x * EPB_;
    const int total = min(EPB_, ME_ - e0);

    __shared__ int hist[NB_];
    __shared__ int lstart[NB_];
    __shared__ int gbase[NB_];
    __shared__ int scanbuf[256];
    __shared__ int pack[EPB_];
    __shared__ unsigned char bkt[EPB_];

    for (int i = t; i < NB_; i += 1024) hist[i] = 0;
    __syncthreads();

    int myb[2], myp[2];
#pragma unroll
    for (int i = 0; i < 2; i++) {
        int e = e0 + i * 1024 + t;
        if (e < ME_) {
            int m = e / E_;
            int row = m * N_ + dst[e];
            myb[i] = row >> 8;
            myp[i] = (src[e] << 8) | (row & 255);
            atomicAdd(&hist[myb[i]], 1);
        } else myb[i] = -1;
    }
    __syncthreads();

    int c = (t < NB_) ? hist[t] : 0;
    if (t < 256) scanbuf[t] = c;
    for (int s = 1; s < 256; s <<= 1) {
        __syncthreads();
        int tmp = (t >= s && t < 256) ? scanbuf[t - s] : 0;
        __syncthreads();
        if (t < 256) scanbuf[t] += tmp;
    }
    __syncthreads();
    if (t < NB_) {
        int pre = scanbuf[t] - c;
        lstart[t] = pre;
        hist[t]   = pre;                            // becomes local cursor
        if (c > 0) gbase[t] = atomicAdd(&bcur[t], c);
    }
    __syncthreads();

#pragma unroll
    for (int i = 0; i < 2; i++) {
        if (myb[i] >= 0) {
            int p = atomicAdd(&hist[myb[i]], 1);
            pack[p] = myp[i];
            bkt[p]  = (unsigned char)myb[i];
        }
    }
    __syncthreads();

    for (int j = t; j < total; j += 1024) {
        int b = bkt[j];
        ebuf[gbase[b] + (j - lstart[b])] = pack[j];
    }
}

// K4: FUSED csr-scatter + aggregate. 4 blocks per window (512 thr = 8 waves);
// block handles a 64-row quarter: scans the window's contiguous ebuf run
// (4x redundant read, L2-resident), builds its quarter's CSR in LDS (ushort
// src ids), then each wave aggregates 8 rows. esrc/rowstart round trip GONE.
__global__ __launch_bounds__(512) void aggregate_win(
    const int* __restrict__ blockoff, const int* __restrict__ ebuf,
    const float* __restrict__ el, const float* __restrict__ er,
    const ushort* __restrict__ feat, const float* __restrict__ bias,
    ushort* __restrict__ z) {
    const int k = blockIdx.x;
    const int w = k >> 2, q = k & 3;                // window, quarter
    const int t = threadIdx.x;
    const int boff = blockoff[w], wend = blockoff[w + 1];

    __shared__ int cur[64];
    __shared__ int rowbeg[65];
    __shared__ ushort lsrc[MAXQ_];

    if (t < 64) cur[t] = 0;
    __syncthreads();
    // count this quarter's edges
    for (int j = boff + t; j < wend; j += 512) {
        int e = ebuf[j];
        int r = e & 255;
        if ((r >> 6) == q) atomicAdd(&cur[r & 63], 1);
    }
    __syncthreads();
    // wave-0 shfl scan of 64 counts
    if (t < 64) {
        int v = cur[t];
        int s = v;
        for (int off = 1; off < 64; off <<= 1) {
            int u = __shfl_up(s, off);
            if (t >= off) s += u;
        }
        rowbeg[t] = s - v;
        cur[t]    = s - v;
        if (t == 63) rowbeg[64] = s;
    }
    __syncthreads();
    // scatter into LDS CSR
    for (int j = boff + t; j < wend; j += 512) {
        int e = ebuf[j];
        int r = e & 255;
        if ((r >> 6) == q) {
            int p = atomicAdd(&cur[r & 63], 1);
            lsrc[p] = (ushort)(e >> 8);
        }
    }
    __syncthreads();

    // aggregate: wave wv handles local rows wv, wv+8, ..., wv+56
    const int wv = t >> 6, lane = t & 63;
    const int head = lane >> 4;
    const int lo = 4 * lane;
    for (int rl = wv; rl < 64; rl += 8) {
        const int g = __builtin_amdgcn_readfirstlane(w * 256 + q * 64 + rl);
        if (g >= MN_) continue;
        const int m = g / N_;
        const int beg = __builtin_amdgcn_readfirstlane(rowbeg[rl]);
        const int end = __builtin_amdgcn_readfirstlane(rowbeg[rl + 1]);
        const float erv = er[(size_t)g * H_ + head];
        const int mN = m * N_;
        const float* elm = el + (size_t)mN * H_;
        const ushort* fm = feat + (size_t)mN * HD_;
        float a0 = 0.f, a1 = 0.f, a2 = 0.f, a3 = 0.f, den = 0.f;

        int j = beg;
        for (; j + 4 <= end; j += 4) {
            int s0 = __builtin_amdgcn_readfirstlane(lsrc[j]);
            int s1 = __builtin_amdgcn_readfirstlane(lsrc[j + 1]);
            int s2 = __builtin_amdgcn_readfirstlane(lsrc[j + 2]);
            int s3 = __builtin_amdgcn_readfirstlane(lsrc[j + 3]);
            float x0 = (elm + (size_t)s0 * H_)[head] + erv;
            float x1 = (elm + (size_t)s1 * H_)[head] + erv;
            float x2 = (elm + (size_t)s2 * H_)[head] + erv;
            float x3 = (elm + (size_t)s3 * H_)[head] + erv;
            ushort4 f0 = *(const ushort4*)(fm + (size_t)s0 * HD_ + lo);
            ushort4 f1 = *(const ushort4*)(fm + (size_t)s1 * HD_ + lo);
            ushort4 f2 = *(const ushort4*)(fm + (size_t)s2 * HD_ + lo);
            ushort4 f3 = *(const ushort4*)(fm + (size_t)s3 * HD_ + lo);
            x0 = x0 > 0.f ? x0 : NEG_SLOPE * x0;
            x1 = x1 > 0.f ? x1 : NEG_SLOPE * x1;
            x2 = x2 > 0.f ? x2 : NEG_SLOPE * x2;
            x3 = x3 > 0.f ? x3 : NEG_SLOPE * x3;
            float e0 = __expf(x0), e1 = __expf(x1), e2 = __expf(x2), e3 = __expf(x3);
            a0 += e0 * h2f(f0.x) + e1 * h2f(f1.x) + e2 * h2f(f2.x) + e3 * h2f(f3.x);
            a1 += e0 * h2f(f0.y) + e1 * h2f(f1.y) + e2 * h2f(f2.y) + e3 * h2f(f3.y);
            a2 += e0 * h2f(f0.z) + e1 * h2f(f1.z) + e2 * h2f(f2.z) + e3 * h2f(f3.z);
            a3 += e0 * h2f(f0.w) + e1 * h2f(f1.w) + e2 * h2f(f2.w) + e3 * h2f(f3.w);
            den += e0 + e1 + e2 + e3;
        }
        for (; j < end; j++) {
            int s = __builtin_amdgcn_readfirstlane(lsrc[j]);
            float x = (elm + (size_t)s * H_)[head] + erv;
            x = x > 0.f ? x : NEG_SLOPE * x;
            float ee = __expf(x);
            ushort4 f4 = *(const ushort4*)(fm + (size_t)s * HD_ + lo);
            a0 += ee * h2f(f4.x);
            a1 += ee * h2f(f4.y);
            a2 += ee * h2f(f4.z);
            a3 += ee * h2f(f4.w);
            den += ee;
        }
        float inv = 1.f / fmaxf(den, 1e-9f);
        float4 b4 = *(const float4*)(bias + m * HD_ + lo);
        ushort4 o;
        o.x = f2bf(a0 * inv + b4.x);
        o.y = f2bf(a1 * inv + b4.y);
        o.z = f2bf(a2 * inv + b4.z);
        o.w = f2bf(a3 * inv + b4.w);
        *(ushort4*)(z + (size_t)g * HD_ + lo) = o;
    }
}

// K6: MFMA semantic attention; fast_tanh + hashed atomics (unchanged).
__global__ __launch_bounds__(128) void semantic_w(
    const ushort* __restrict__ z, const ushort* __restrict__ W1T,
    const float* __restrict__ b1, const float* __restrict__ W2,
    float* __restrict__ wsum) {
    const int tx   = threadIdx.x;
    const int wv   = tx >> 6;
    const int lane = tx & 63;
    const int l15  = lane & 15;
    const int kq   = lane >> 4;
    const int rowbase = blockIdx.x * 32;
    const int m = rowbase / N_;                     // 32 | 20000 -> uniform

    __shared__ ushort zs[32][HD_ + 8];
#pragma unroll
    for (int i = 0; i < 16; i++) {
        int u4 = i * 128 + tx;                      // ushort4 idx 0..2047
        int r = u4 >> 6, c = (u4 & 63) * 4;
        *(ushort4*)&zs[r][c] = *(const ushort4*)&z[(size_t)(rowbase + r) * HD_ + c];
    }
    __syncthreads();

    f32x4 acc[8];
#pragma unroll
    for (int g = 0; g < 8; g++) acc[g] = {0.f, 0.f, 0.f, 0.f};

    const int arow = wv * 16 + l15;
    for (int k0 = 0; k0 < HD_; k0 += 32) {
        short8 a = *(const short8*)&zs[arow][k0 + kq * 8];
#pragma unroll
        for (int g = 0; g < 8; g++) {
            short8 b = *(const short8*)&W1T[(size_t)(16 * g + l15) * HD_ + k0 + kq * 8];
            acc[g] = __builtin_amdgcn_mfma_f32_16x16x32_bf16(a, b, acc[g], 0, 0, 0);
        }
    }

    float local = 0.f;
#pragma unroll
    for (int g = 0; g < 8; g++) {
        int col = 16 * g + l15;
        float bb = b1[col], w2 = W2[col];
        local += fast_tanh(acc[g][0] + bb) * w2;
        local += fast_tanh(acc[g][1] + bb) * w2;
        local += fast_tanh(acc[g][2] + bb) * w2;
        local += fast_tanh(acc[g][3] + bb) * w2;
    }
    for (int off = 32; off; off >>= 1) local += __shfl_down(local, off);
    __shared__ float red[2];
    if (lane == 0) red[wv] = local;
    __syncthreads();
    if (tx == 0) {
        int slot = (m * WS_SLOTS_ + (blockIdx.x & (WS_SLOTS_ - 1))) * 16;  // 64 B apart
        atomicAdd(&wsum[slot], red[0] + red[1]);
    }
}

// K7: out[n][c] = sum_m beta[m] * bf2f(z[m][n][c]); beta from hashed wsum slots.
__global__ __launch_bounds__(256) void final_out(
    const ushort* __restrict__ z, const float* __restrict__ wsum,
    float* __restrict__ out) {
    int idx = blockIdx.x * 256 + threadIdx.x;
    if (idx >= N_ * HD_ / 4) return;
    float w0 = 0.f, w1 = 0.f, w2 = 0.f;
#pragma unroll
    for (int k = 0; k < WS_SLOTS_; k++) {           // uniform -> scalar loads
        w0 += wsum[(0 * WS_SLOTS_ + k) * 16];
        w1 += wsum[(1 * WS_SLOTS_ + k) * 16];
        w2 += wsum[(2 * WS_SLOTS_ + k) * 16];
    }
    float mx = fmaxf(w0, fmaxf(w1, w2));
    float e0 = __expf((w0 - mx) / (float)N_);
    float e1 = __expf((w1 - mx) / (float)N_);
    float e2 = __expf((w2 - mx) / (float)N_);
    float sinv = 1.f / (e0 + e1 + e2);
    float b0 = e0 * sinv, b1 = e1 * sinv, b2 = e2 * sinv;
    ushort4 q0 = *(const ushort4*)&z[(size_t)idx * 4];
    ushort4 q1 = *(const ushort4*)&z[(size_t)N_ * HD_ + (size_t)idx * 4];
    ushort4 q2 = *(const ushort4*)&z[(size_t)2 * N_ * HD_ + (size_t)idx * 4];
    float4 o;
    o.x = b0 * bf2f(q0.x) + b1 * bf2f(q1.x) + b2 * bf2f(q2.x);
    o.y = b0 * bf2f(q0.y) + b1 * bf2f(q1.y) + b2 * bf2f(q2.y);
    o.z = b0 * bf2f(q0.z) + b1 * bf2f(q1.z) + b2 * bf2f(q2.z);
    o.w = b0 * bf2f(q0.w) + b1 * bf2f(q1.w) + b2 * bf2f(q2.w);
    *(float4*)&out[(size_t)idx * 4] = o;
}

extern "C" void kernel_launch(void* const* d_in, const int* in_sizes, int n_in,
                              void* d_out, int out_size, void* d_ws, size_t ws_size,
                              hipStream_t stream) {
    const float* h    = (const float*)d_in[0];
    const int*   src  = (const int*)d_in[1];
    const int*   dst  = (const int*)d_in[2];
    const float* W    = (const float*)d_in[3];
    const float* al   = (const float*)d_in[4];
    const float* ar   = (const float*)d_in[5];
    const float* bias = (const float*)d_in[6];
    const float* W1   = (const float*)d_in[7];
    const float* b1   = (const float*)d_in[8];
    const float* W2   = (const float*)d_in[9];

    char* ws = (char*)d_ws;
    ushort* feat     = (ushort*)(ws + FEAT_OFF);
    ushort* z        = (ushort*)(ws + Z_OFF);
    int*    ebuf     = (int*)(ws + EBUF_OFF);
    float*  el       = (float*)(ws + EL_OFF);
    float*  er       = (float*)(ws + ER_OFF);
    int*    wincnt   = (int*)(ws + WINC_OFF);
    float*  wsum     = (float*)(ws + WSUM_OFF);
    int*    blockoff = (int*)(ws + BO_OFF);
    ushort* w1t      = (ushort*)(ws + W1T_OFF);
    int*    bcur     = (int*)(ws + BCUR_OFF);
    ushort* wt       = (ushort*)(ws + WT_OFF);

    // zero wincnt + wsum (contiguous 4 KB)
    hipMemsetAsync(ws + WINC_OFF, 0, 1024 + 3072, stream);

    prep_hist235<<<32 + NPB_, 1024, 0, stream>>>(W, W1, dst, wt, w1t, wincnt);
    feat_gemm_mfma<<<dim3(N_ / 32, M_), 128, 0, stream>>>(h, wt, al, ar, feat, el, er);
    scan2w<<<1, 256, 0, stream>>>(wincnt, blockoff, bcur);
    edge_partition<<<NPB_, 1024, 0, stream>>>(src, dst, bcur, ebuf);
    aggregate_win<<<NB_ * 4, 512, 0, stream>>>(blockoff, ebuf, el, er, feat, bias, z);
    semantic_w<<<MN_ / 32, 128, 0, stream>>>(z, w1t, b1, W2, wsum);
    final_out<<<N_ * HD_ / 4 / 256, 256, 0, stream>>>(z, wsum, (float*)d_out);
}

// Round 18
// 248.522 us; speedup vs baseline: 1.0814x; 1.0814x over previous
//
#include <hip/hip_runtime.h>
#include <hip/hip_bf16.h>

// Problem constants
constexpr int N_   = 20000;
constexpr int E_   = 320000;
constexpr int M_   = 3;
constexpr int KIN  = 128;   // in_size
constexpr int H_   = 4;     // heads
constexpr int D_   = 64;    // per-head dim
constexpr int HD_  = 256;   // H*D
constexpr int HID_ = 128;   // semantic hidden
constexpr int MN_  = M_ * N_;   // 60000 segments
constexpr int ME_  = M_ * E_;   // 960000 edges
constexpr int NB_  = (MN_ + 255) / 256;  // 235 windows (256 rows each)
constexpr int EPB_ = 2048;               // edges per partition block
constexpr int NPB_ = (ME_ + EPB_ - 1) / EPB_;  // 469 partition blocks
constexpr int WS_SLOTS_ = 16;            // wsum slots per metapath (64 B apart)
#define NEG_SLOPE 0.2f

// Workspace layout (bytes)
constexpr size_t FEAT_OFF = 0;           // ushort[M*N*HD]  = 30,720,000 (FP16 feat)
constexpr size_t Z_OFF    = 30720000;    // ushort[M*N*HD]  (bf16 z)
constexpr size_t EBUF_OFF = 46080000;    // int   [M*E]     =  3,840,000 (window-grouped packed edges)
constexpr size_t EL_OFF   = 92160000;    // float [M*N*H]   =    960,000
constexpr size_t ER_OFF   = 93120000;    // float [M*N*H]   =    960,000
constexpr size_t ESRC_OFF = 94080000;    // int   [M*E]     =  3,840,000 (CSR src ids)
constexpr size_t ROW_OFF  = 105600000;   // int   [MN+1]    =    240,064 (within-window prefix)
constexpr size_t WINC_OFF = 106080064;   // int   [256]     window edge counts   } memset
constexpr size_t WSUM_OFF = 106081088;   // float [3*16*16] = 3,072 hashed slots } together
constexpr size_t BO_OFF   = 106084160;   // int   [256]  window offsets (blockoff[NB_]=ME_)
constexpr size_t W1T_OFF  = 106085184;   // ushort[HID*HD] = 65,536 (bf16 W1 transposed)
constexpr size_t BCUR_OFF = 106150720;   // int   [256]    window write fronts (init by scan2w)
// wt overlaps the z region: z is written only by aggregate_csr, which runs
// strictly after feat_gemm_mfma (sole consumer of wt).
constexpr size_t WT_OFF   = Z_OFF;       // ushort[M*HD*KIN] = 196,608

typedef __attribute__((ext_vector_type(8))) short short8;   // 8 bf16 (4 VGPRs)
typedef __attribute__((ext_vector_type(4))) float f32x4;    // MFMA accumulator

__device__ __forceinline__ float bf2f(ushort u) {
    union { unsigned int i; float f; } v; v.i = ((unsigned int)u) << 16; return v.f;
}
__device__ __forceinline__ ushort f2bf(float f) {
    union { float f; unsigned int i; } v; v.f = f;
    unsigned int i = v.i;
    unsigned int r = (i + 0x7fffu + ((i >> 16) & 1u)) >> 16;   // RNE
    return (ushort)r;
}
__device__ __forceinline__ ushort f2h(float f) {
    _Float16 h = (_Float16)f;
    ushort u; __builtin_memcpy(&u, &h, 2); return u;
}
__device__ __forceinline__ float h2f(ushort u) {
    _Float16 h; __builtin_memcpy(&h, &u, 2); return (float)h;   // fpext -> fma_mix fodder
}
// fast tanh: 1 - 2/(e^{2x}+1)
__device__ __forceinline__ float fast_tanh(float x) {
    float e = __expf(2.f * x);
    return 1.f - 2.f * __builtin_amdgcn_rcpf(e + 1.f);
}

// K0: fused prep (W->WT sigma-permuted bf16, W1->W1T bf16) + 235-bin window
// histogram (LDS + merged atomics). 1024 threads/block.
__global__ __launch_bounds__(1024) void prep_hist235(
    const float* __restrict__ W, const float* __restrict__ W1,
    const int* __restrict__ dst, ushort* __restrict__ wt,
    ushort* __restrict__ w1t, int* __restrict__ wincnt) {
    const int b = blockIdx.x, t = threadIdx.x;
    if (b < 32) {                                   // prep: 32*4096 = 131072 floats
        int f = b * 4096 + t * 4;
        if (f < 3 * HD_ * KIN) {                    // wt: 98304 elements
            int m = f >> 15, r = f & 32767, n = r >> 7, k0 = r & 127;
            int c = ((n & 15) << 4) | (n >> 4);     // sigma(n), self-inverse
            const float* src = W + (size_t)m * KIN * HD_ + c;
            ushort4 o;
            o.x = f2bf(src[(size_t)(k0 + 0) * HD_]);
            o.y = f2bf(src[(size_t)(k0 + 1) * HD_]);
            o.z = f2bf(src[(size_t)(k0 + 2) * HD_]);
            o.w = f2bf(src[(size_t)(k0 + 3) * HD_]);
            *(ushort4*)&wt[f] = o;
        } else {                                    // w1t: 32768 elements
            int f2 = f - 3 * HD_ * KIN;
            int n = f2 >> 8, k0 = f2 & 255;
            const float* src = W1 + n;
            ushort4 o;
            o.x = f2bf(src[(size_t)(k0 + 0) * HID_]);
            o.y = f2bf(src[(size_t)(k0 + 1) * HID_]);
            o.z = f2bf(src[(size_t)(k0 + 2) * HID_]);
            o.w = f2bf(src[(size_t)(k0 + 3) * HID_]);
            *(ushort4*)&w1t[f2] = o;
        }
    } else {                                        // histogram: 2048 edges/block
        __shared__ int hcnt[NB_];
        const int e0 = (b - 32) * EPB_;
        for (int i = t; i < NB_; i += 1024) hcnt[i] = 0;
        __syncthreads();
#pragma unroll
        for (int i = 0; i < 2; i++) {
            int e = e0 + i * 1024 + t;
            if (e < ME_) {
                int m = e / E_;
                int row = m * N_ + dst[e];
                atomicAdd(&hcnt[row >> 8], 1);
            }
        }
        __syncthreads();
        for (int i = t; i < NB_; i += 1024)
            if (hcnt[i]) atomicAdd(&wincnt[i], hcnt[i]);
    }
}

// K1: MFMA feat = h @ W[m] + fused el/er epilogue; feat stored FP16.
__global__ __launch_bounds__(128) void feat_gemm_mfma(
    const float* __restrict__ h, const ushort* __restrict__ wt,
    const float* __restrict__ al, const float* __restrict__ ar,
    ushort* __restrict__ feat, float* __restrict__ el, float* __restrict__ er) {
    const int tx   = threadIdx.x;
    const int wv   = tx >> 6;
    const int lane = tx & 63;
    const int l15  = lane & 15, kq = lane >> 4;
    const int m    = blockIdx.y;
    const int blockrow = blockIdx.x * 32;
    const int rowbase  = blockrow + wv * 16;

    __shared__ ushort hsm[32][KIN + 8];             // 8,704 B
#pragma unroll
    for (int i = 0; i < 8; i++) {
        int f4 = i * 128 + tx;                      // float4 idx 0..1023
        int r = f4 >> 5, k = (f4 & 31) * 4;
        float4 v = *(const float4*)&h[(size_t)(blockrow + r) * KIN + k];
        ushort4 o;
        o.x = f2bf(v.x); o.y = f2bf(v.y); o.z = f2bf(v.z); o.w = f2bf(v.w);
        *(ushort4*)&hsm[r][k] = o;
    }
    __syncthreads();

    f32x4 acc[16];
#pragma unroll
    for (int g = 0; g < 16; g++) acc[g] = {0.f, 0.f, 0.f, 0.f};

    const ushort* wb = wt + ((size_t)m * HD_ + l15) * KIN + kq * 8;
    const int arow = wv * 16 + l15;
    for (int kb = 0; kb < KIN; kb += 32) {
        short8 a = *(const short8*)&hsm[arow][kb + kq * 8];
#pragma unroll
        for (int g = 0; g < 16; g++) {
            short8 b = *(const short8*)&wb[(size_t)(16 * g) * KIN + kb];
            acc[g] = __builtin_amdgcn_mfma_f32_16x16x32_bf16(a, b, acc[g], 0, 0, 0);
        }
    }

    // feat store (fp16): acc[g][reg] = feat[row=rowbase+kq*4+reg][col=l15*16+g]
#pragma unroll
    for (int reg = 0; reg < 4; reg++) {
        int row = rowbase + kq * 4 + reg;
        short8 v0, v1;
#pragma unroll
        for (int g = 0; g < 8; g++) {
            v0[g] = (short)f2h(acc[g][reg]);
            v1[g] = (short)f2h(acc[g + 8][reg]);
        }
        size_t fo = ((size_t)m * N_ + row) * HD_ + l15 * 16;
        *(short8*)&feat[fo]     = v0;
        *(short8*)&feat[fo + 8] = v1;
    }

    const int head = l15 >> 2;
    const float* alp = al + ((size_t)(m * H_ + head)) * D_ + ((l15 & 3) << 4);
    const float* arp = ar + ((size_t)(m * H_ + head)) * D_ + ((l15 & 3) << 4);
    float4 av0 = *(const float4*)&alp[0],  av1 = *(const float4*)&alp[4];
    float4 av2 = *(const float4*)&alp[8],  av3 = *(const float4*)&alp[12];
    float4 rv0 = *(const float4*)&arp[0],  rv1 = *(const float4*)&arp[4];
    float4 rv2 = *(const float4*)&arp[8],  rv3 = *(const float4*)&arp[12];
    float pl[4], pr[4];
#pragma unroll
    for (int reg = 0; reg < 4; reg++) {
        pl[reg] = acc[0][reg]*av0.x + acc[1][reg]*av0.y + acc[2][reg]*av0.z + acc[3][reg]*av0.w
                + acc[4][reg]*av1.x + acc[5][reg]*av1.y + acc[6][reg]*av1.z + acc[7][reg]*av1.w
                + acc[8][reg]*av2.x + acc[9][reg]*av2.y + acc[10][reg]*av2.z + acc[11][reg]*av2.w
                + acc[12][reg]*av3.x + acc[13][reg]*av3.y + acc[14][reg]*av3.z + acc[15][reg]*av3.w;
        pr[reg] = acc[0][reg]*rv0.x + acc[1][reg]*rv0.y + acc[2][reg]*rv0.z + acc[3][reg]*rv0.w
                + acc[4][reg]*rv1.x + acc[5][reg]*rv1.y + acc[6][reg]*rv1.z + acc[7][reg]*rv1.w
                + acc[8][reg]*rv2.x + acc[9][reg]*rv2.y + acc[10][reg]*rv2.z + acc[11][reg]*rv2.w
                + acc[12][reg]*rv3.x + acc[13][reg]*rv3.y + acc[14][reg]*rv3.z + acc[15][reg]*rv3.w;
    }
#pragma unroll
    for (int off = 2; off; off >>= 1) {
#pragma unroll
        for (int reg = 0; reg < 4; reg++) {
            pl[reg] += __shfl_down(pl[reg], off, 4);
            pr[reg] += __shfl_down(pr[reg], off, 4);
        }
    }
    if ((l15 & 3) == 0) {
#pragma unroll
        for (int reg = 0; reg < 4; reg++) {
            int row = rowbase + kq * 4 + reg;
            int o = (m * N_ + row) * H_ + head;
            el[o] = pl[reg];
            er[o] = pr[reg];
        }
    }
}

// K2: scan 235 window counts -> blockoff + bcur; blockoff[NB_]=ME_; patch rowstart[MN_].
__global__ __launch_bounds__(256) void scan2w(const int* __restrict__ wincnt,
                                              int* __restrict__ blockoff,
                                              int* __restrict__ bcur,
                                              int* __restrict__ rowstart) {
    __shared__ int lds[256];
    const int t = threadIdx.x;
    int v = (t < NB_) ? wincnt[t] : 0;
    lds[t] = v;
    for (int s = 1; s < 256; s <<= 1) {
        __syncthreads();
        int tmp = (t >= s) ? lds[t - s] : 0;
        __syncthreads();
        lds[t] += tmp;
    }
    __syncthreads();
    if (t < NB_) {
        int off = lds[t] - v;
        blockoff[t] = off;
        bcur[t]     = off;
        if (t == NB_ - 1) rowstart[MN_] = ME_ - off;
    }
    if (t == NB_) blockoff[NB_] = ME_;
}

// K3: radix partition — 1024 threads.
__global__ __launch_bounds__(1024) void edge_partition(
    const int* __restrict__ src, const int* __restrict__ dst,
    int* __restrict__ bcur, int* __restrict__ ebuf) {
    const int t = threadIdx.x;
    const int e0 = blockIdx.x * EPB_;
    const int total = min(EPB_, ME_ - e0);

    __shared__ int hist[NB_];
    __shared__ int lstart[NB_];
    __shared__ int gbase[NB_];
    __shared__ int scanbuf[256];
    __shared__ int pack[EPB_];
    __shared__ unsigned char bkt[EPB_];

    for (int i = t; i < NB_; i += 1024) hist[i] = 0;
    __syncthreads();

    int myb[2], myp[2];
#pragma unroll
    for (int i = 0; i < 2; i++) {
        int e = e0 + i * 1024 + t;
        if (e < ME_) {
            int m = e / E_;
            int row = m * N_ + dst[e];
            myb[i] = row >> 8;
            myp[i] = (src[e] << 8) | (row & 255);
            atomicAdd(&hist[myb[i]], 1);
        } else myb[i] = -1;
    }
    __syncthreads();

    int c = (t < NB_) ? hist[t] : 0;
    if (t < 256) scanbuf[t] = c;
    for (int s = 1; s < 256; s <<= 1) {
        __syncthreads();
        int tmp = (t >= s && t < 256) ? scanbuf[t - s] : 0;
        __syncthreads();
        if (t < 256) scanbuf[t] += tmp;
    }
    __syncthreads();
    if (t < NB_) {
        int pre = scanbuf[t] - c;
        lstart[t] = pre;
        hist[t]   = pre;                            // becomes local cursor
        if (c > 0) gbase[t] = atomicAdd(&bcur[t], c);
    }
    __syncthreads();

#pragma unroll
    for (int i = 0; i < 2; i++) {
        if (myb[i] >= 0) {
            int p = atomicAdd(&hist[myb[i]], 1);
            pack[p] = myp[i];
            bkt[p]  = (unsigned char)myb[i];
        }
    }
    __syncthreads();

    for (int j = t; j < total; j += 1024) {
        int b = bkt[j];
        ebuf[gbase[b] + (j - lstart[b])] = pack[j];
    }
}

// K4: csr_scatter2 — 1024 threads.
__global__ __launch_bounds__(1024) void csr_scatter2(
    const int* __restrict__ blockoff, const int* __restrict__ ebuf,
    int* __restrict__ rowstart, int* __restrict__ esrc) {
    const int k = blockIdx.x;
    const int t = threadIdx.x;
    __shared__ int cur[256];
    __shared__ int scanb[256];
    if (t < 256) cur[t] = 0;
    __syncthreads();
    const int boff = blockoff[k];
    const int wend = blockoff[k + 1];
    for (int j = boff + t; j < wend; j += 1024)
        atomicAdd(&cur[ebuf[j] & 255], 1);
    __syncthreads();
    int v = (t < 256) ? cur[t] : 0;
    if (t < 256) scanb[t] = v;
    for (int s = 1; s < 256; s <<= 1) {
        __syncthreads();
        int tmp = (t >= s && t < 256) ? scanb[t - s] : 0;
        __syncthreads();
        if (t < 256) scanb[t] += tmp;
    }
    __syncthreads();
    if (t < 256) {
        int pre = scanb[t] - v;                     // within-window exclusive prefix
        int rowi = k * 256 + t;
        if (rowi < MN_) rowstart[rowi] = pre;
        cur[t] = pre;                               // becomes cursor
    }
    __syncthreads();
    for (int j = boff + t; j < wend; j += 1024) {
        int e = ebuf[j];
        int p = atomicAdd(&cur[e & 255], 1) + boff;
        esrc[p] = e >> 8;
    }
}

// K5: wave per (m, dst), scalarized addressing, 8-wide gather pipeline
// (r16 was 4-wide at VALU 49.6% / HBM 47% — latency-bound middle ground;
// deeper MLP is the standard lever).
__global__ __launch_bounds__(256) void aggregate_csr(
    const int* __restrict__ rowstart, const int* __restrict__ blockoff,
    const int* __restrict__ esrc, const float* __restrict__ el,
    const float* __restrict__ er, const ushort* __restrict__ feat,
    const float* __restrict__ bias, ushort* __restrict__ z) {
    const int g = __builtin_amdgcn_readfirstlane(blockIdx.x * 4 + (threadIdx.x >> 6));
    const int lane = threadIdx.x & 63;
    const int m = g / N_;
    const int head = lane >> 4;
    const int beg = __builtin_amdgcn_readfirstlane(rowstart[g] + blockoff[g >> 8]);
    const int end = __builtin_amdgcn_readfirstlane(rowstart[g + 1] + blockoff[(g + 1) >> 8]);
    const float erv = er[(size_t)g * H_ + head];
    const int mN = m * N_;
    const float* elm = el + (size_t)mN * H_;
    const ushort* fm = feat + (size_t)mN * HD_;
    const int lo = 4 * lane;
    float a0 = 0.f, a1 = 0.f, a2 = 0.f, a3 = 0.f, den = 0.f;

    int j = beg;
    for (; j + 8 <= end; j += 8) {
        int s[8];
#pragma unroll
        for (int i = 0; i < 8; i++) s[i] = __builtin_amdgcn_readfirstlane(esrc[j + i]);
        float x[8];
        ushort4 f[8];
#pragma unroll
        for (int i = 0; i < 8; i++) {
            x[i] = (elm + (size_t)s[i] * H_)[head] + erv;
            f[i] = *(const ushort4*)(fm + (size_t)s[i] * HD_ + lo);
        }
#pragma unroll
        for (int i = 0; i < 8; i++) {
            float xi = x[i];
            xi = xi > 0.f ? xi : NEG_SLOPE * xi;
            float ei = __expf(xi);
            a0 += ei * h2f(f[i].x);
            a1 += ei * h2f(f[i].y);
            a2 += ei * h2f(f[i].z);
            a3 += ei * h2f(f[i].w);
            den += ei;
        }
    }
    for (; j + 4 <= end; j += 4) {
        int s0 = __builtin_amdgcn_readfirstlane(esrc[j]);
        int s1 = __builtin_amdgcn_readfirstlane(esrc[j + 1]);
        int s2 = __builtin_amdgcn_readfirstlane(esrc[j + 2]);
        int s3 = __builtin_amdgcn_readfirstlane(esrc[j + 3]);
        float x0 = (elm + (size_t)s0 * H_)[head] + erv;
        float x1 = (elm + (size_t)s1 * H_)[head] + erv;
        float x2 = (elm + (size_t)s2 * H_)[head] + erv;
        float x3 = (elm + (size_t)s3 * H_)[head] + erv;
        ushort4 f0 = *(const ushort4*)(fm + (size_t)s0 * HD_ + lo);
        ushort4 f1 = *(const ushort4*)(fm + (size_t)s1 * HD_ + lo);
        ushort4 f2 = *(const ushort4*)(fm + (size_t)s2 * HD_ + lo);
        ushort4 f3 = *(const ushort4*)(fm + (size_t)s3 * HD_ + lo);
        x0 = x0 > 0.f ? x0 : NEG_SLOPE * x0;
        x1 = x1 > 0.f ? x1 : NEG_SLOPE * x1;
        x2 = x2 > 0.f ? x2 : NEG_SLOPE * x2;
        x3 = x3 > 0.f ? x3 : NEG_SLOPE * x3;
        float e0 = __expf(x0), e1 = __expf(x1), e2 = __expf(x2), e3 = __expf(x3);
        a0 += e0 * h2f(f0.x) + e1 * h2f(f1.x) + e2 * h2f(f2.x) + e3 * h2f(f3.x);
        a1 += e0 * h2f(f0.y) + e1 * h2f(f1.y) + e2 * h2f(f2.y) + e3 * h2f(f3.y);
        a2 += e0 * h2f(f0.z) + e1 * h2f(f1.z) + e2 * h2f(f2.z) + e3 * h2f(f3.z);
        a3 += e0 * h2f(f0.w) + e1 * h2f(f1.w) + e2 * h2f(f2.w) + e3 * h2f(f3.w);
        den += e0 + e1 + e2 + e3;
    }
    for (; j < end; j++) {
        int s = __builtin_amdgcn_readfirstlane(esrc[j]);
        float x = (elm + (size_t)s * H_)[head] + erv;
        x = x > 0.f ? x : NEG_SLOPE * x;
        float ee = __expf(x);
        ushort4 f4 = *(const ushort4*)(fm + (size_t)s * HD_ + lo);
        a0 += ee * h2f(f4.x);
        a1 += ee * h2f(f4.y);
        a2 += ee * h2f(f4.z);
        a3 += ee * h2f(f4.w);
        den += ee;
    }
    float inv = 1.f / fmaxf(den, 1e-9f);
    float4 b4 = *(const float4*)(bias + m * HD_ + lo);
    ushort4 o;
    o.x = f2bf(a0 * inv + b4.x);
    o.y = f2bf(a1 * inv + b4.y);
    o.z = f2bf(a2 * inv + b4.z);
    o.w = f2bf(a3 * inv + b4.w);
    *(ushort4*)(z + (size_t)g * HD_ + lo) = o;
}

// K6: MFMA semantic attention; fast_tanh + hashed atomics (unchanged).
__global__ __launch_bounds__(128) void semantic_w(
    const ushort* __restrict__ z, const ushort* __restrict__ W1T,
    const float* __restrict__ b1, const float* __restrict__ W2,
    float* __restrict__ wsum) {
    const int tx   = threadIdx.x;
    const int wv   = tx >> 6;
    const int lane = tx & 63;
    const int l15  = lane & 15;
    const int kq   = lane >> 4;
    const int rowbase = blockIdx.x * 32;
    const int m = rowbase / N_;                     // 32 | 20000 -> uniform

    __shared__ ushort zs[32][HD_ + 8];
#pragma unroll
    for (int i = 0; i < 16; i++) {
        int u4 = i * 128 + tx;                      // ushort4 idx 0..2047
        int r = u4 >> 6, c = (u4 & 63) * 4;
        *(ushort4*)&zs[r][c] = *(const ushort4*)&z[(size_t)(rowbase + r) * HD_ + c];
    }
    __syncthreads();

    f32x4 acc[8];
#pragma unroll
    for (int g = 0; g < 8; g++) acc[g] = {0.f, 0.f, 0.f, 0.f};

    const int arow = wv * 16 + l15;
    for (int k0 = 0; k0 < HD_; k0 += 32) {
        short8 a = *(const short8*)&zs[arow][k0 + kq * 8];
#pragma unroll
        for (int g = 0; g < 8; g++) {
            short8 b = *(const short8*)&W1T[(size_t)(16 * g + l15) * HD_ + k0 + kq * 8];
            acc[g] = __builtin_amdgcn_mfma_f32_16x16x32_bf16(a, b, acc[g], 0, 0, 0);
        }
    }

    float local = 0.f;
#pragma unroll
    for (int g = 0; g < 8; g++) {
        int col = 16 * g + l15;
        float bb = b1[col], w2 = W2[col];
        local += fast_tanh(acc[g][0] + bb) * w2;
        local += fast_tanh(acc[g][1] + bb) * w2;
        local += fast_tanh(acc[g][2] + bb) * w2;
        local += fast_tanh(acc[g][3] + bb) * w2;
    }
    for (int off = 32; off; off >>= 1) local += __shfl_down(local, off);
    __shared__ float red[2];
    if (lane == 0) red[wv] = local;
    __syncthreads();
    if (tx == 0) {
        int slot = (m * WS_SLOTS_ + (blockIdx.x & (WS_SLOTS_ - 1))) * 16;  // 64 B apart
        atomicAdd(&wsum[slot], red[0] + red[1]);
    }
}

// K7: out[n][c] = sum_m beta[m] * bf2f(z[m][n][c]); beta from hashed wsum slots.
__global__ __launch_bounds__(256) void final_out(
    const ushort* __restrict__ z, const float* __restrict__ wsum,
    float* __restrict__ out) {
    int idx = blockIdx.x * 256 + threadIdx.x;
    if (idx >= N_ * HD_ / 4) return;
    float w0 = 0.f, w1 = 0.f, w2 = 0.f;
#pragma unroll
    for (int k = 0; k < WS_SLOTS_; k++) {           // uniform -> scalar loads
        w0 += wsum[(0 * WS_SLOTS_ + k) * 16];
        w1 += wsum[(1 * WS_SLOTS_ + k) * 16];
        w2 += wsum[(2 * WS_SLOTS_ + k) * 16];
    }
    float mx = fmaxf(w0, fmaxf(w1, w2));
    float e0 = __expf((w0 - mx) / (float)N_);
    float e1 = __expf((w1 - mx) / (float)N_);
    float e2 = __expf((w2 - mx) / (float)N_);
    float sinv = 1.f / (e0 + e1 + e2);
    float b0 = e0 * sinv, b1 = e1 * sinv, b2 = e2 * sinv;
    ushort4 q0 = *(const ushort4*)&z[(size_t)idx * 4];
    ushort4 q1 = *(const ushort4*)&z[(size_t)N_ * HD_ + (size_t)idx * 4];
    ushort4 q2 = *(const ushort4*)&z[(size_t)2 * N_ * HD_ + (size_t)idx * 4];
    float4 o;
    o.x = b0 * bf2f(q0.x) + b1 * bf2f(q1.x) + b2 * bf2f(q2.x);
    o.y = b0 * bf2f(q0.y) + b1 * bf2f(q1.y) + b2 * bf2f(q2.y);
    o.z = b0 * bf2f(q0.z) + b1 * bf2f(q1.z) + b2 * bf2f(q2.z);
    o.w = b0 * bf2f(q0.w) + b1 * bf2f(q1.w) + b2 * bf2f(q2.w);
    *(float4*)&out[(size_t)idx * 4] = o;
}

extern "C" void kernel_launch(void* const* d_in, const int* in_sizes, int n_in,
                              void* d_out, int out_size, void* d_ws, size_t ws_size,
                              hipStream_t stream) {
    const float* h    = (const float*)d_in[0];
    const int*   src  = (const int*)d_in[1];
    const int*   dst  = (const int*)d_in[2];
    const float* W    = (const float*)d_in[3];
    const float* al   = (const float*)d_in[4];
    const float* ar   = (const float*)d_in[5];
    const float* bias = (const float*)d_in[6];
    const float* W1   = (const float*)d_in[7];
    const float* b1   = (const float*)d_in[8];
    const float* W2   = (const float*)d_in[9];

    char* ws = (char*)d_ws;
    ushort* feat     = (ushort*)(ws + FEAT_OFF);
    ushort* z        = (ushort*)(ws + Z_OFF);
    int*    ebuf     = (int*)(ws + EBUF_OFF);
    float*  el       = (float*)(ws + EL_OFF);
    float*  er       = (float*)(ws + ER_OFF);
    int*    esrc     = (int*)(ws + ESRC_OFF);
    int*    rowstart = (int*)(ws + ROW_OFF);
    int*    wincnt   = (int*)(ws + WINC_OFF);
    float*  wsum     = (float*)(ws + WSUM_OFF);
    int*    blockoff = (int*)(ws + BO_OFF);
    ushort* w1t      = (ushort*)(ws + W1T_OFF);
    int*    bcur     = (int*)(ws + BCUR_OFF);
    ushort* wt       = (ushort*)(ws + WT_OFF);

    // zero wincnt + wsum (contiguous 4 KB)
    hipMemsetAsync(ws + WINC_OFF, 0, 1024 + 3072, stream);

    prep_hist235<<<32 + NPB_, 1024, 0, stream>>>(W, W1, dst, wt, w1t, wincnt);
    feat_gemm_mfma<<<dim3(N_ / 32, M_), 128, 0, stream>>>(h, wt, al, ar, feat, el, er);
    scan2w<<<1, 256, 0, stream>>>(wincnt, blockoff, bcur, rowstart);
    edge_partition<<<NPB_, 1024, 0, stream>>>(src, dst, bcur, ebuf);
    csr_scatter2<<<NB_, 1024, 0, stream>>>(blockoff, ebuf, rowstart, esrc);
    aggregate_csr<<<MN_ / 4, 256, 0, stream>>>(rowstart, blockoff, esrc, el, er, feat, bias, z);
    semantic_w<<<MN_ / 32, 128, 0, stream>>>(z, w1t, b1, W2, wsum);
    final_out<<<N_ * HD_ / 4 / 256, 256, 0, stream>>>(z, wsum, (float*)d_out);
}